// Round 13
// baseline (284.527 us; speedup 1.0000x reference)
//
#include <hip/hip_runtime.h>
#include <hip/hip_fp16.h>

// CompressibleFluidLoss: out[i] = mean_x + mean_y + (p[i]-p_prev[i])/dt,
// vp = v*p per node; means are masked scatter-means over edges at src.
//
// Round 13 (on r12): bucket_reduce's per-record 11-step LDS binary search
// (log2 MAXCHUNK) was ~1/3 of its time (VALUBusy 30%). Replace with
// contiguous per-thread partitioning: ONE binary search per thread for the
// starting chunk, then a register-cached forward walk (cur/pre/cend/goff).
// Exactly-balanced 16 recs/thread, 2 cache lines each. Rest unchanged:
// fp16 vph gather (4MB L2-resident), packed-f64 LDS accumulator.

#define NPB      2048   // nodes per bucket
#define NPB_LOG  11
#define NBUCK_MAX 512
#define CE       4096   // edges per chunk
#define CB       1024   // chunk_sort block threads
#define EPT      4      // edges per thread
#define CCAP     4608   // record capacity per chunk region (mean 4096, +11s)
#define MAXCHUNK 2048
#define K_OFF    1073741824.0   // 2^30

typedef unsigned long long ull;

// ---------------- fast path ----------------

__global__ void node_pre_fast(const float2* __restrict__ v,
                              const float* __restrict__ p,
                              float2* __restrict__ vpf,
                              __half2* __restrict__ vph,
                              double2* __restrict__ side,
                              int* __restrict__ oflow, int N) {
    int i = blockIdx.x * blockDim.x + threadIdx.x;
    int stride = gridDim.x * blockDim.x;
    for (; i < N; i += stride) {
        float2 vi = v[i];
        float pi = p[i];
        float2 vp = make_float2(vi.x * pi, vi.y * pi);
        vpf[i] = vp;
        vph[i] = __float22half2_rn(vp);
        side[i] = make_double2(0.0, 0.0);
    }
    if (blockIdx.x == 0 && threadIdx.x == 0) *oflow = 0;
}

__device__ __forceinline__ void route_rec(uint2 r, int k, size_t rb, int slot,
                                          uint2* __restrict__ recs,
                                          const float2* __restrict__ vpf,
                                          double2* __restrict__ side,
                                          int* __restrict__ oflow) {
    if (slot < CCAP) { recs[rb + slot] = r; return; }
    // overflow (never in practice): exact packed-f64 global side accumulator
    unsigned sl = r.x & (NPB - 1u);
    bool diry = (r.x >> 11) & 1u;
    int d = (int)(r.x >> 12);
    float a = __uint_as_float(r.y);
    int s = k * NPB + (int)sl;
    float2 vpd = vpf[d], vs = vpf[s];
    float c = (diry ? vpd.y - vs.y : vpd.x - vs.x) / a;
    unsafeAtomicAdd(diry ? &side[s].y : &side[s].x, (double)c + K_OFF);
    atomicOr(oflow, 1);
}

__global__ __launch_bounds__(CB) void chunk_sort(
        const float2* __restrict__ ea,
        const int* __restrict__ src_idx,
        const int* __restrict__ dst_idx,
        const float2* __restrict__ vpf,
        uint2* __restrict__ recs,
        unsigned short* __restrict__ off_mat,
        unsigned short* __restrict__ cnt_mat,
        double2* __restrict__ side,
        int* __restrict__ oflow,
        int nbuck, int E) {
    __shared__ uint2 stage[CCAP];        // 36 KB
    __shared__ int hist[NBUCK_MAX];      // 2 KB
    __shared__ int tl[NBUCK_MAX];        // 2 KB
    __shared__ int cur[NBUCK_MAX];       // 2 KB
    int c = blockIdx.x, t = threadIdx.x;
    int e0 = c * CE;

    uint2 R0[EPT], R1[EPT];
    int K[EPT], NR[EPT];
#pragma unroll
    for (int i = 0; i < EPT; ++i) {
        int e = e0 + i * CB + t;         // coalesced per sub-iteration
        NR[i] = 0; K[i] = 0;
        if (e < E) {
            float2 a = ea[e];
            bool mx = (a.x != 0.f);
            bool my = (a.y != 0.f);
            if (mx || my) {
                int s = src_idx[e];
                int d = dst_idx[e];
                K[i] = s >> NPB_LOG;
                unsigned sl = (unsigned)(s & (NPB - 1));
                unsigned dm = (unsigned)d << 12;
                NR[i] = (int)mx + (int)my;
                uint2 rx = make_uint2(sl | dm, __float_as_uint(a.x));
                uint2 ry = make_uint2(sl | 0x800u | dm, __float_as_uint(a.y));
                R0[i] = mx ? rx : ry;
                R1[i] = ry;
            }
        }
    }
    if (t < nbuck) hist[t] = 0;
    __syncthreads();
#pragma unroll
    for (int i = 0; i < EPT; ++i)
        if (NR[i]) atomicAdd(&hist[K[i]], NR[i]);
    __syncthreads();
    // inclusive scan hist -> tl over nbuck (<= 512)
    if (t < nbuck) tl[t] = hist[t];
    __syncthreads();
    for (int off = 1; off < NBUCK_MAX; off <<= 1) {
        int x = 0;
        if (t < nbuck && t >= off) x = tl[t - off];
        __syncthreads();
        if (t < nbuck) tl[t] += x;
        __syncthreads();
    }
    int total = tl[nbuck - 1];
    if (t < nbuck) {
        int excl = tl[t] - hist[t];
        cur[t] = excl;
        off_mat[(size_t)c * nbuck + t] = (unsigned short)excl;
        cnt_mat[(size_t)c * nbuck + t] = (unsigned short)hist[t];
    }
    __syncthreads();
    size_t rb = (size_t)c * CCAP;
    if (total <= CCAP) {
        // stage grouped by bucket, then flush linearly (coalesced)
#pragma unroll
        for (int i = 0; i < EPT; ++i)
            if (NR[i]) {
                int slot = atomicAdd(&cur[K[i]], NR[i]);
                stage[slot] = R0[i];
                if (NR[i] == 2) stage[slot + 1] = R1[i];
            }
        __syncthreads();
        for (int j = t; j < total; j += CB) recs[rb + j] = stage[j];
    } else {
        // overflow regime (never in practice)
#pragma unroll
        for (int i = 0; i < EPT; ++i)
            if (NR[i]) {
                int slot = atomicAdd(&cur[K[i]], NR[i]);
                route_rec(R0[i], K[i], rb, slot, recs, vpf, side, oflow);
                if (NR[i] == 2) route_rec(R1[i], K[i], rb, slot + 1, recs, vpf, side, oflow);
            }
    }
}

__global__ __launch_bounds__(1024) void bucket_reduce(
        const uint2* __restrict__ recs,
        const unsigned short* __restrict__ off_mat,
        const unsigned short* __restrict__ cnt_mat,
        const float2* __restrict__ vpf,
        const __half2* __restrict__ vph,
        const double2* __restrict__ side,
        const int* __restrict__ oflow,
        const float* __restrict__ p,
        const float* __restrict__ p_prev,
        const float* __restrict__ dt_ptr,
        float* __restrict__ out,
        int nchunk, int nbuck, int N) {
    __shared__ float2 vps[NPB];      // 16 KB (f32 source side)
    __shared__ double2 acc[NPB];     // 32 KB packed (sum + cnt*2^30)
    __shared__ int glen[MAXCHUNK];   // 8 KB -> inclusive prefix after scan
    __shared__ int goff[MAXCHUNK];   // 8 KB
    __shared__ int s_of;
    int k = blockIdx.x, t = threadIdx.x;
    int g0 = k * NPB;
    for (int i = t; i < NPB; i += 1024) {
        int g = g0 + i;
        vps[i] = (g < N) ? vpf[g] : make_float2(0.f, 0.f);
        acc[i] = make_double2(0.0, 0.0);
    }
    if (t == 0) s_of = *oflow;
    for (int c = t; c < MAXCHUNK; c += 1024) {
        int len = 0, off = 0;
        if (c < nchunk) {
            off = __builtin_nontemporal_load(&off_mat[(size_t)c * nbuck + k]);
            int cnt = __builtin_nontemporal_load(&cnt_mat[(size_t)c * nbuck + k]);
            len = min(cnt, max(0, CCAP - off));   // clamp overflow'd tail
        }
        goff[c] = off;
        glen[c] = len;
    }
    __syncthreads();
    // inclusive scan glen over MAXCHUNK (2048) with 1024 threads
    for (int off = 1; off < MAXCHUNK; off <<= 1) {
        int i0 = t, i1 = t + 1024;
        int x0 = (i0 >= off) ? glen[i0 - off] : 0;
        int x1 = glen[i1 - off];
        __syncthreads();
        glen[i0] += x0;
        glen[i1] += x1;
        __syncthreads();
    }
    int total = glen[MAXCHUNK - 1];
    const ull* recs64 = (const ull*)recs;
    // contiguous per-thread partition: one search, then register walk
    int per = (total + 1023) >> 10;
    int i0 = t * per;
    int i1 = min(i0 + per, total);
    if (i0 < i1) {
        int lo = 0, hi = nchunk - 1;       // first chunk with glen[chunk] > i0
        while (lo < hi) {
            int mid = (lo + hi) >> 1;
            if (glen[mid] > i0) hi = mid; else lo = mid + 1;
        }
        int cur = lo;
        int pre = cur ? glen[cur - 1] : 0;
        int cend = glen[cur];
        int gof = goff[cur];
        for (int idx = i0; idx < i1; ++idx) {
            while (idx >= cend) {           // advance chunk (register compare)
                ++cur;
                pre = cend;
                cend = glen[cur];
                gof = goff[cur];
            }
            ull rv = __builtin_nontemporal_load(
                &recs64[(size_t)cur * CCAP + gof + (idx - pre)]);
            unsigned m = (unsigned)rv;
            float a = __uint_as_float((unsigned)(rv >> 32));
            int sl = (int)(m & (NPB - 1u));
            bool diry = (m >> 11) & 1u;
            int d = (int)(m >> 12);
            float2 vpd = __half22float2(vph[d]);   // 4B gather; 4MB, L2-hit
            float2 vs = vps[sl];
            float c = (diry ? vpd.y - vs.y : vpd.x - vs.x) / a;
            unsafeAtomicAdd(diry ? &acc[sl].y : &acc[sl].x, (double)c + K_OFF);
        }
    }
    __syncthreads();
    float inv_dt = 1.0f / dt_ptr[0];
    for (int i = t; i < NPB; i += 1024) {
        int g = g0 + i;
        if (g < N) {
            double2 A = acc[i];
            if (s_of) {
                double2 S = side[g];
                A.x += S.x; A.y += S.y;
            }
            double cx = rint(A.x * (1.0 / K_OFF));
            double sx = A.x - cx * K_OFF;
            double cy = rint(A.y * (1.0 / K_OFF));
            double sy = A.y - cy * K_OFF;
            out[g] = (float)(sx / fmax(cx, 1.0)) + (float)(sy / fmax(cy, 1.0))
                   + (p[g] - p_prev[g]) * inv_dt;
        }
    }
}

// ---------------- fallback path (round-5: f64-packed atomics, 390us) -------

__global__ void fb_node_pre(const float2* __restrict__ v,
                            const float* __restrict__ p,
                            float2* __restrict__ vp,
                            double2* __restrict__ acc, int N) {
    int i = blockIdx.x * blockDim.x + threadIdx.x;
    int stride = gridDim.x * blockDim.x;
    for (; i < N; i += stride) {
        float2 vi = v[i];
        float pi = p[i];
        vp[i] = make_float2(vi.x * pi, vi.y * pi);
        acc[i] = make_double2(0.0, 0.0);
    }
}

__global__ void fb_edge_scatter(const float2* __restrict__ vp,
                                const float2* __restrict__ ea,
                                const int* __restrict__ src_idx,
                                const int* __restrict__ dst_idx,
                                double2* __restrict__ acc, int E) {
    int e = blockIdx.x * blockDim.x + threadIdx.x;
    if (e >= E) return;
    float2 a = ea[e];
    bool mx = (a.x != 0.f);
    bool my = (a.y != 0.f);
    if (!mx && !my) return;
    int s = src_idx[e];
    int d = dst_idx[e];
    float2 vs = vp[s];
    float2 vd = vp[d];
    double* basep = (double*)&acc[s];
    if (mx) unsafeAtomicAdd(basep + 0, (double)((vd.x - vs.x) / a.x) + K_OFF);
    if (my) unsafeAtomicAdd(basep + 1, (double)((vd.y - vs.y) / a.y) + K_OFF);
}

__global__ void fb_node_final(const double2* __restrict__ acc,
                              const float* __restrict__ p,
                              const float* __restrict__ p_prev,
                              const float* __restrict__ dt_ptr,
                              float* __restrict__ out, int N) {
    int i = blockIdx.x * blockDim.x + threadIdx.x;
    int stride = gridDim.x * blockDim.x;
    float inv_dt = 1.0f / dt_ptr[0];
    for (; i < N; i += stride) {
        double2 A = acc[i];
        double cx = rint(A.x * (1.0 / K_OFF));
        double sx = A.x - cx * K_OFF;
        double cy = rint(A.y * (1.0 / K_OFF));
        double sy = A.y - cy * K_OFF;
        out[i] = (float)(sx / fmax(cx, 1.0)) + (float)(sy / fmax(cy, 1.0))
               + (p[i] - p_prev[i]) * inv_dt;
    }
}

// ---------------- launch ----------------

extern "C" void kernel_launch(void* const* d_in, const int* in_sizes, int n_in,
                              void* d_out, int out_size, void* d_ws, size_t ws_size,
                              hipStream_t stream) {
    const float2* v_x    = (const float2*)d_in[0];
    const float*  p_x    = (const float*)d_in[2];
    const float*  p_prev = (const float*)d_in[3];
    const float*  dt     = (const float*)d_in[9];
    const float2* ea     = (const float2*)d_in[10];
    const int*    eidx   = (const int*)d_in[11];

    const int N = in_sizes[2];
    const int E = in_sizes[10] / 2;
    const int* src_idx = eidx;
    const int* dst_idx = eidx + E;

    const int nbuck  = (N + NPB - 1) >> NPB_LOG;
    const int nchunk = (E + CE - 1) / CE;

    // ws: vpf 8 | vph 4 | side 16 | flag | off 2 | cnt 2 | recs 75.5 MB
    char* w = (char*)d_ws;
    float2*  vpf     = (float2*)w;    w += (size_t)N * sizeof(float2);
    __half2* vph     = (__half2*)w;   w += (size_t)N * sizeof(__half2);
    double2* side    = (double2*)w;   w += (size_t)N * sizeof(double2);
    int*     oflow   = (int*)w;       w += 16;
    unsigned short* off_mat = (unsigned short*)w;  w += (size_t)nchunk * nbuck * sizeof(unsigned short);
    unsigned short* cnt_mat = (unsigned short*)w;  w += (size_t)nchunk * nbuck * sizeof(unsigned short);
    w = (char*)(((uintptr_t)w + 15) & ~(uintptr_t)15);
    uint2*   recs    = (uint2*)w;     w += (size_t)nchunk * CCAP * sizeof(uint2);
    size_t need_fast = (size_t)(w - (char*)d_ws);

    if (nbuck <= NBUCK_MAX && nchunk <= MAXCHUNK && N <= (1 << 20)
        && ws_size >= need_fast) {
        node_pre_fast<<<2048, 256, 0, stream>>>(v_x, p_x, vpf, vph, side, oflow, N);
        chunk_sort<<<nchunk, CB, 0, stream>>>(ea, src_idx, dst_idx, vpf, recs,
                                              off_mat, cnt_mat, side, oflow,
                                              nbuck, E);
        bucket_reduce<<<nbuck, 1024, 0, stream>>>(recs, off_mat, cnt_mat,
                                                  vpf, vph, side, oflow,
                                                  p_x, p_prev, dt,
                                                  (float*)d_out, nchunk, nbuck, N);
    } else {
        float2*  fvp  = (float2*)d_ws;
        double2* facc = (double2*)((char*)d_ws + (size_t)N * sizeof(float2));
        fb_node_pre<<<2048, 256, 0, stream>>>(v_x, p_x, fvp, facc, N);
        fb_edge_scatter<<<(E + 255) / 256, 256, 0, stream>>>(
            fvp, ea, src_idx, dst_idx, facc, E);
        fb_node_final<<<2048, 256, 0, stream>>>(
            facc, p_x, p_prev, dt, (float*)d_out, N);
    }
}

// Round 14
// 153.737 us; speedup vs baseline: 1.8507x; 1.8507x over previous
//
#include <hip/hip_runtime.h>
#include <hip/hip_fp16.h>

// CompressibleFluidLoss: out[i] = mean_x + mean_y + (p[i]-p_prev[i])/dt,
// vp = v*p per node; means are masked scatter-means over edges at src.
//
// Round 14 (r12 base): r13 proved per-thread contiguous slices break wave
// coalescing (FETCH 180->645MB). Keep r12's interleaved record access
// (lane-consecutive = coalesced); replace the per-record 11-step binary
// search with an O(1) LDS hint table: hint[j] = chunk of record 8j (2K
// binary searches once per block), then a <=2-step forward walk per record.
// Also drop vpf: vps staged from v,p directly; overflow path recomputes.

#define NPB      2048   // nodes per bucket
#define NPB_LOG  11
#define NBUCK_MAX 512
#define CE       4096   // edges per chunk
#define CB       1024   // chunk_sort block threads
#define EPT      4      // edges per thread
#define CCAP     4608   // record capacity per chunk region (mean 4096, +11s)
#define MAXCHUNK 2048
#define NHINT    4096
#define K_OFF    1073741824.0   // 2^30

typedef unsigned long long ull;

// ---------------- fast path ----------------

__global__ void node_pre_fast(const float2* __restrict__ v,
                              const float* __restrict__ p,
                              __half2* __restrict__ vph,
                              double2* __restrict__ side,
                              int* __restrict__ oflow, int N) {
    int i = blockIdx.x * blockDim.x + threadIdx.x;
    int stride = gridDim.x * blockDim.x;
    for (; i < N; i += stride) {
        float2 vi = v[i];
        float pi = p[i];
        vph[i] = __float22half2_rn(make_float2(vi.x * pi, vi.y * pi));
        side[i] = make_double2(0.0, 0.0);
    }
    if (blockIdx.x == 0 && threadIdx.x == 0) *oflow = 0;
}

__device__ __forceinline__ void route_rec(uint2 r, int k, size_t rb, int slot,
                                          uint2* __restrict__ recs,
                                          const float2* __restrict__ v,
                                          const float* __restrict__ p,
                                          double2* __restrict__ side,
                                          int* __restrict__ oflow) {
    if (slot < CCAP) { recs[rb + slot] = r; return; }
    // overflow (never in practice): exact packed-f64 global side accumulator
    unsigned sl = r.x & (NPB - 1u);
    bool diry = (r.x >> 11) & 1u;
    int d = (int)(r.x >> 12);
    float a = __uint_as_float(r.y);
    int s = k * NPB + (int)sl;
    float2 vd = v[d], vs = v[s];
    float pd = p[d], ps = p[s];
    float c = (diry ? vd.y * pd - vs.y * ps : vd.x * pd - vs.x * ps) / a;
    unsafeAtomicAdd(diry ? &side[s].y : &side[s].x, (double)c + K_OFF);
    atomicOr(oflow, 1);
}

__global__ __launch_bounds__(CB) void chunk_sort(
        const float2* __restrict__ ea,
        const int* __restrict__ src_idx,
        const int* __restrict__ dst_idx,
        const float2* __restrict__ v,
        const float* __restrict__ p,
        uint2* __restrict__ recs,
        unsigned short* __restrict__ off_mat,
        unsigned short* __restrict__ cnt_mat,
        double2* __restrict__ side,
        int* __restrict__ oflow,
        int nbuck, int E) {
    __shared__ uint2 stage[CCAP];        // 36 KB
    __shared__ int hist[NBUCK_MAX];      // 2 KB
    __shared__ int tl[NBUCK_MAX];        // 2 KB
    __shared__ int cur[NBUCK_MAX];       // 2 KB
    int c = blockIdx.x, t = threadIdx.x;
    int e0 = c * CE;

    uint2 R0[EPT], R1[EPT];
    int K[EPT], NR[EPT];
#pragma unroll
    for (int i = 0; i < EPT; ++i) {
        int e = e0 + i * CB + t;         // coalesced per sub-iteration
        NR[i] = 0; K[i] = 0;
        if (e < E) {
            float2 a = ea[e];
            bool mx = (a.x != 0.f);
            bool my = (a.y != 0.f);
            if (mx || my) {
                int s = src_idx[e];
                int d = dst_idx[e];
                K[i] = s >> NPB_LOG;
                unsigned sl = (unsigned)(s & (NPB - 1));
                unsigned dm = (unsigned)d << 12;
                NR[i] = (int)mx + (int)my;
                uint2 rx = make_uint2(sl | dm, __float_as_uint(a.x));
                uint2 ry = make_uint2(sl | 0x800u | dm, __float_as_uint(a.y));
                R0[i] = mx ? rx : ry;
                R1[i] = ry;
            }
        }
    }
    if (t < nbuck) hist[t] = 0;
    __syncthreads();
#pragma unroll
    for (int i = 0; i < EPT; ++i)
        if (NR[i]) atomicAdd(&hist[K[i]], NR[i]);
    __syncthreads();
    // inclusive scan hist -> tl over nbuck (<= 512)
    if (t < nbuck) tl[t] = hist[t];
    __syncthreads();
    for (int off = 1; off < NBUCK_MAX; off <<= 1) {
        int x = 0;
        if (t < nbuck && t >= off) x = tl[t - off];
        __syncthreads();
        if (t < nbuck) tl[t] += x;
        __syncthreads();
    }
    int total = tl[nbuck - 1];
    if (t < nbuck) {
        int excl = tl[t] - hist[t];
        cur[t] = excl;
        off_mat[(size_t)c * nbuck + t] = (unsigned short)excl;
        cnt_mat[(size_t)c * nbuck + t] = (unsigned short)hist[t];
    }
    __syncthreads();
    size_t rb = (size_t)c * CCAP;
    if (total <= CCAP) {
        // stage grouped by bucket, then flush linearly (coalesced)
#pragma unroll
        for (int i = 0; i < EPT; ++i)
            if (NR[i]) {
                int slot = atomicAdd(&cur[K[i]], NR[i]);
                stage[slot] = R0[i];
                if (NR[i] == 2) stage[slot + 1] = R1[i];
            }
        __syncthreads();
        for (int j = t; j < total; j += CB) recs[rb + j] = stage[j];
    } else {
        // overflow regime (never in practice)
#pragma unroll
        for (int i = 0; i < EPT; ++i)
            if (NR[i]) {
                int slot = atomicAdd(&cur[K[i]], NR[i]);
                route_rec(R0[i], K[i], rb, slot, recs, v, p, side, oflow);
                if (NR[i] == 2) route_rec(R1[i], K[i], rb, slot + 1, recs, v, p, side, oflow);
            }
    }
}

__global__ __launch_bounds__(1024) void bucket_reduce(
        const uint2* __restrict__ recs,
        const unsigned short* __restrict__ off_mat,
        const unsigned short* __restrict__ cnt_mat,
        const float2* __restrict__ v,
        const float* __restrict__ p,
        const __half2* __restrict__ vph,
        const double2* __restrict__ side,
        const int* __restrict__ oflow,
        const float* __restrict__ p_prev,
        const float* __restrict__ dt_ptr,
        float* __restrict__ out,
        int nchunk, int nbuck, int N) {
    __shared__ float2 vps[NPB];            // 16 KB (f32 source side, from v*p)
    __shared__ double2 acc[NPB];           // 32 KB packed (sum + cnt*2^30)
    __shared__ int glen[MAXCHUNK];         // 8 KB -> inclusive prefix
    __shared__ int goff[MAXCHUNK];         // 8 KB
    __shared__ unsigned short hint[NHINT]; // 8 KB: record 8j -> chunk
    __shared__ int s_of;
    int k = blockIdx.x, t = threadIdx.x;
    int g0 = k * NPB;
    for (int i = t; i < NPB; i += 1024) {
        int g = g0 + i;
        float2 vi = (g < N) ? v[g] : make_float2(0.f, 0.f);
        float pi = (g < N) ? p[g] : 0.f;
        vps[i] = make_float2(vi.x * pi, vi.y * pi);
        acc[i] = make_double2(0.0, 0.0);
    }
    if (t == 0) s_of = *oflow;
    for (int c = t; c < MAXCHUNK; c += 1024) {
        int len = 0, off = 0;
        if (c < nchunk) {
            off = __builtin_nontemporal_load(&off_mat[(size_t)c * nbuck + k]);
            int cnt = __builtin_nontemporal_load(&cnt_mat[(size_t)c * nbuck + k]);
            len = min(cnt, max(0, CCAP - off));   // clamp overflow'd tail
        }
        goff[c] = off;
        glen[c] = len;
    }
    __syncthreads();
    // inclusive scan glen over MAXCHUNK (2048) with 1024 threads
    for (int off = 1; off < MAXCHUNK; off <<= 1) {
        int i0 = t, i1 = t + 1024;
        int x0 = (i0 >= off) ? glen[i0 - off] : 0;
        int x1 = glen[i1 - off];
        __syncthreads();
        glen[i0] += x0;
        glen[i1] += x1;
        __syncthreads();
    }
    int total = glen[MAXCHUNK - 1];
    // build hint table: hint[j] = first chunk with glen[chunk] > 8j
    int nh = min((total + 7) >> 3, NHINT);
    for (int j = t; j < nh; j += 1024) {
        int target = j << 3;
        int lo = 0, hi = nchunk - 1;
        while (lo < hi) {
            int mid = (lo + hi) >> 1;
            if (glen[mid] > target) hi = mid; else lo = mid + 1;
        }
        hint[j] = (unsigned short)lo;
    }
    __syncthreads();
    const ull* recs64 = (const ull*)recs;
    // interleaved (coalesced) record walk with O(1) chunk lookup
    for (int idx = t; idx < total; idx += 1024) {
        int j = idx >> 3;
        int cur;
        if (j < NHINT) {
            cur = hint[j];
        } else {                             // beyond hint range (never)
            int lo = 0, hi = nchunk - 1;
            while (lo < hi) {
                int mid = (lo + hi) >> 1;
                if (glen[mid] > idx) hi = mid; else lo = mid + 1;
            }
            cur = lo;
        }
        while (glen[cur] <= idx) ++cur;      // <= ~2 steps
        int pre = cur ? glen[cur - 1] : 0;
        ull rv = __builtin_nontemporal_load(
            &recs64[(size_t)cur * CCAP + goff[cur] + (idx - pre)]);
        unsigned m = (unsigned)rv;
        float a = __uint_as_float((unsigned)(rv >> 32));
        int sl = (int)(m & (NPB - 1u));
        bool diry = (m >> 11) & 1u;
        int d = (int)(m >> 12);
        float2 vpd = __half22float2(vph[d]);   // 4B gather; 4MB set, L2-hit
        float2 vs = vps[sl];
        float c = (diry ? vpd.y - vs.y : vpd.x - vs.x) / a;
        unsafeAtomicAdd(diry ? &acc[sl].y : &acc[sl].x, (double)c + K_OFF);
    }
    __syncthreads();
    float inv_dt = 1.0f / dt_ptr[0];
    for (int i = t; i < NPB; i += 1024) {
        int g = g0 + i;
        if (g < N) {
            double2 A = acc[i];
            if (s_of) {
                double2 S = side[g];
                A.x += S.x; A.y += S.y;
            }
            double cx = rint(A.x * (1.0 / K_OFF));
            double sx = A.x - cx * K_OFF;
            double cy = rint(A.y * (1.0 / K_OFF));
            double sy = A.y - cy * K_OFF;
            out[g] = (float)(sx / fmax(cx, 1.0)) + (float)(sy / fmax(cy, 1.0))
                   + (p[g] - p_prev[g]) * inv_dt;
        }
    }
}

// ---------------- fallback path (round-5: f64-packed atomics, 390us) -------

__global__ void fb_node_pre(const float2* __restrict__ v,
                            const float* __restrict__ p,
                            float2* __restrict__ vp,
                            double2* __restrict__ acc, int N) {
    int i = blockIdx.x * blockDim.x + threadIdx.x;
    int stride = gridDim.x * blockDim.x;
    for (; i < N; i += stride) {
        float2 vi = v[i];
        float pi = p[i];
        vp[i] = make_float2(vi.x * pi, vi.y * pi);
        acc[i] = make_double2(0.0, 0.0);
    }
}

__global__ void fb_edge_scatter(const float2* __restrict__ vp,
                                const float2* __restrict__ ea,
                                const int* __restrict__ src_idx,
                                const int* __restrict__ dst_idx,
                                double2* __restrict__ acc, int E) {
    int e = blockIdx.x * blockDim.x + threadIdx.x;
    if (e >= E) return;
    float2 a = ea[e];
    bool mx = (a.x != 0.f);
    bool my = (a.y != 0.f);
    if (!mx && !my) return;
    int s = src_idx[e];
    int d = dst_idx[e];
    float2 vs = vp[s];
    float2 vd = vp[d];
    double* basep = (double*)&acc[s];
    if (mx) unsafeAtomicAdd(basep + 0, (double)((vd.x - vs.x) / a.x) + K_OFF);
    if (my) unsafeAtomicAdd(basep + 1, (double)((vd.y - vs.y) / a.y) + K_OFF);
}

__global__ void fb_node_final(const double2* __restrict__ acc,
                              const float* __restrict__ p,
                              const float* __restrict__ p_prev,
                              const float* __restrict__ dt_ptr,
                              float* __restrict__ out, int N) {
    int i = blockIdx.x * blockDim.x + threadIdx.x;
    int stride = gridDim.x * blockDim.x;
    float inv_dt = 1.0f / dt_ptr[0];
    for (; i < N; i += stride) {
        double2 A = acc[i];
        double cx = rint(A.x * (1.0 / K_OFF));
        double sx = A.x - cx * K_OFF;
        double cy = rint(A.y * (1.0 / K_OFF));
        double sy = A.y - cy * K_OFF;
        out[i] = (float)(sx / fmax(cx, 1.0)) + (float)(sy / fmax(cy, 1.0))
               + (p[i] - p_prev[i]) * inv_dt;
    }
}

// ---------------- launch ----------------

extern "C" void kernel_launch(void* const* d_in, const int* in_sizes, int n_in,
                              void* d_out, int out_size, void* d_ws, size_t ws_size,
                              hipStream_t stream) {
    const float2* v_x    = (const float2*)d_in[0];
    const float*  p_x    = (const float*)d_in[2];
    const float*  p_prev = (const float*)d_in[3];
    const float*  dt     = (const float*)d_in[9];
    const float2* ea     = (const float2*)d_in[10];
    const int*    eidx   = (const int*)d_in[11];

    const int N = in_sizes[2];
    const int E = in_sizes[10] / 2;
    const int* src_idx = eidx;
    const int* dst_idx = eidx + E;

    const int nbuck  = (N + NPB - 1) >> NPB_LOG;
    const int nchunk = (E + CE - 1) / CE;

    // ws: vph 4 | side 16 | flag | off 2 | cnt 2 | recs 75.5 MB  (~100 MB)
    char* w = (char*)d_ws;
    __half2* vph     = (__half2*)w;   w += (size_t)N * sizeof(__half2);
    double2* side    = (double2*)w;   w += (size_t)N * sizeof(double2);
    int*     oflow   = (int*)w;       w += 16;
    unsigned short* off_mat = (unsigned short*)w;  w += (size_t)nchunk * nbuck * sizeof(unsigned short);
    unsigned short* cnt_mat = (unsigned short*)w;  w += (size_t)nchunk * nbuck * sizeof(unsigned short);
    w = (char*)(((uintptr_t)w + 15) & ~(uintptr_t)15);
    uint2*   recs    = (uint2*)w;     w += (size_t)nchunk * CCAP * sizeof(uint2);
    size_t need_fast = (size_t)(w - (char*)d_ws);

    if (nbuck <= NBUCK_MAX && nchunk <= MAXCHUNK && N <= (1 << 20)
        && ws_size >= need_fast) {
        node_pre_fast<<<2048, 256, 0, stream>>>(v_x, p_x, vph, side, oflow, N);
        chunk_sort<<<nchunk, CB, 0, stream>>>(ea, src_idx, dst_idx, v_x, p_x,
                                              recs, off_mat, cnt_mat, side,
                                              oflow, nbuck, E);
        bucket_reduce<<<nbuck, 1024, 0, stream>>>(recs, off_mat, cnt_mat,
                                                  v_x, p_x, vph, side, oflow,
                                                  p_prev, dt,
                                                  (float*)d_out, nchunk, nbuck, N);
    } else {
        float2*  fvp  = (float2*)d_ws;
        double2* facc = (double2*)((char*)d_ws + (size_t)N * sizeof(float2));
        fb_node_pre<<<2048, 256, 0, stream>>>(v_x, p_x, fvp, facc, N);
        fb_edge_scatter<<<(E + 255) / 256, 256, 0, stream>>>(
            fvp, ea, src_idx, dst_idx, facc, E);
        fb_node_final<<<2048, 256, 0, stream>>>(
            facc, p_x, p_prev, dt, (float*)d_out, N);
    }
}